// Round 14
// baseline (321.677 us; speedup 1.0000x reference)
//
#include <hip/hip_runtime.h>

#define BB 16
#define NN 1000
#define DD 256
#define LL 3
#define MAXNZ 256
#define MROWS (BB * NN)
#define SPLIT_SCALE 2048.0f
#define INV_SPLIT 4.8828125e-4f

typedef _Float16 f16x8 __attribute__((ext_vector_type(8)));
typedef _Float16 f16x2 __attribute__((ext_vector_type(2)));
typedef float f32x4 __attribute__((ext_vector_type(4)));

union H8 { f16x8 v; f16x2 p[4]; _Float16 h[8]; int4 i4; unsigned int w[4]; };

#if defined(__has_builtin)
#if __has_builtin(__builtin_amdgcn_fdot2)
#define HAS_FDOT2 1
#endif
#endif

__device__ __forceinline__ float dot2f(f16x2 a, f16x2 b, float c) {
#ifdef HAS_FDOT2
    return __builtin_amdgcn_fdot2(a, b, c, false);
#else
    return fmaf((float)a[0], (float)b[0], fmaf((float)a[1], (float)b[1], c));
#endif
}

__device__ __forceinline__ void fmix2(float& alo, float& ahi,
                                      unsigned int pk, float s) {
    asm("v_fma_mix_f32 %0, %1, %2, %0 op_sel:[0,0,0] op_sel_hi:[1,0,0]"
        : "+v"(alo) : "v"(pk), "v"(s));
    asm("v_fma_mix_f32 %0, %1, %2, %0 op_sel:[1,0,0] op_sel_hi:[1,0,0]"
        : "+v"(ahi) : "v"(pk), "v"(s));
}

// ---------------------------------------------------------------------------
// Kernel 0 (fused setup): [0,160) convert_w, [160,2160) convert_x,
// [2160,6160) build_sparse.
// ---------------------------------------------------------------------------
__global__ __launch_bounds__(256) void setup_all(
    const float* __restrict__ W_list, const float* __restrict__ dense_W,
    const float* __restrict__ final_W,
    _Float16* __restrict__ wt_hi, _Float16* __restrict__ wt_lo,
    const float* __restrict__ x_in,
    _Float16* __restrict__ xh, _Float16* __restrict__ xl,
    const float* __restrict__ contacts,
    int* __restrict__ idx, int* __restrict__ cnt, float* __restrict__ adiag)
{
    __shared__ float T[64][68];
    int bid = blockIdx.x;
    int t = threadIdx.x;

    if (bid < 160) {
        int mat = bid >> 4;
        int tile = bid & 15;
        int tk = (tile >> 2) * 64, tn = (tile & 3) * 64;
        const float* src = (mat < 3) ? (W_list + (size_t)mat * 65536)
                         : (mat < 9) ? (dense_W + (size_t)(mat - 3) * 65536)
                                     : final_W;
        {
            int k = t >> 2, nc = (t & 3) * 16;
            const float* sp = src + (size_t)(tk + k) * 256 + tn + nc;
            *(float4*)&T[k][nc + 0]  = *(const float4*)(sp + 0);
            *(float4*)&T[k][nc + 4]  = *(const float4*)(sp + 4);
            *(float4*)&T[k][nc + 8]  = *(const float4*)(sp + 8);
            *(float4*)&T[k][nc + 12] = *(const float4*)(sp + 12);
        }
        __syncthreads();
        int n = t >> 2, kc = (t & 3) * 16;
        H8 hh0, hh1, ll0, ll1;
        #pragma unroll
        for (int i = 0; i < 16; ++i) {
            float x = T[kc + i][n];
            _Float16 hi = (_Float16)x;
            _Float16 lo = (_Float16)((x - (float)hi) * SPLIT_SCALE);
            if (i < 8) { hh0.h[i] = hi; ll0.h[i] = lo; }
            else       { hh1.h[i - 8] = hi; ll1.h[i - 8] = lo; }
        }
        size_t o = (size_t)mat * 65536 + (size_t)(tn + n) * 256 + tk + kc;
        *(int4*)(wt_hi + o)     = hh0.i4;
        *(int4*)(wt_hi + o + 8) = hh1.i4;
        *(int4*)(wt_lo + o)     = ll0.i4;
        *(int4*)(wt_lo + o + 8) = ll1.i4;
    } else if (bid < 2160) {
        size_t gid = (size_t)(bid - 160) * 256 + t;
        const float* p = x_in + gid * 8;
        float4 a = *(const float4*)p;
        float4 b = *(const float4*)(p + 4);
        float xs[8] = {a.x, a.y, a.z, a.w, b.x, b.y, b.z, b.w};
        H8 hh, ll;
        #pragma unroll
        for (int i = 0; i < 8; ++i) {
            _Float16 h = (_Float16)xs[i];
            hh.h[i] = h;
            ll.h[i] = (_Float16)((xs[i] - (float)h) * SPLIT_SCALE);
        }
        *(int4*)(xh + gid * 8) = hh.i4;
        *(int4*)(xl + gid * 8) = ll.i4;
    } else {
        int wave = (int)(((size_t)(bid - 2160) * 256 + t) >> 6);
        int lane = t & 63;
        int b = wave / NN;
        int i = wave - b * NN;
        const float* row = contacts + (size_t)b * NN * NN + (size_t)i * NN;
        int* out = idx + (size_t)wave * MAXNZ;
        int count = 0;
        for (int j0 = 0; j0 < NN; j0 += 64) {
            int j = j0 + lane;
            float v = (j < NN) ? row[j] : 0.0f;
            bool p = (v != 0.0f) && (j != i);
            unsigned long long bal = __ballot(p);
            if (p) {
                int pre = __popcll(bal & ((1ull << lane) - 1ull));
                out[count + pre] = j;
            }
            count += __popcll(bal);
        }
        if (lane == 0) {
            cnt[wave] = count;
            adiag[wave] = row[i] + 1.0f;
        }
    }
}

// ---------------------------------------------------------------------------
// Kernel 2: sparse attention aggregate v8 (round-13, frozen).
// ---------------------------------------------------------------------------
__global__ __launch_bounds__(256, 3) void sparse_agg(
    const _Float16* __restrict__ yhi,
    const _Float16* __restrict__ xhi, const _Float16* __restrict__ xlo,
    const int* __restrict__ idx, const int* __restrict__ cnt,
    const float* __restrict__ adiag,
    _Float16* __restrict__ ohi, _Float16* __restrict__ olo)
{
    int bid = blockIdx.x;
    int xcd = bid & 7;
    int chunk = bid >> 3;
    int row = xcd * 2000 + chunk * 4 + (int)(threadIdx.x >> 6);
    row = __builtin_amdgcn_readfirstlane(row);
    int lane = threadIdx.x & 63;
    int g = lane >> 4, s = lane & 15;
    int b = row / NN;

    const _Float16* yp = yhi + (size_t)row * DD + s * 8;
    H8 yh0, yh1;
    yh0.i4 = *(const int4*)yp;
    yh1.i4 = *(const int4*)(yp + 128);

    const _Float16* xph = xhi + (size_t)row * DD + s * 8;
    const _Float16* xpl = xlo + (size_t)row * DD + s * 8;
    H8 xih0, xih1, xil0, xil1;
    xih0.i4 = *(const int4*)xph;       xih1.i4 = *(const int4*)(xph + 128);
    xil0.i4 = *(const int4*)xpl;       xil1.i4 = *(const int4*)(xpl + 128);
    float xi[16];
    #pragma unroll
    for (int u = 0; u < 8; ++u) {
        xi[u]     = fmaf((float)xil0.h[u], INV_SPLIT, (float)xih0.h[u]);
        xi[8 + u] = fmaf((float)xil1.h[u], INV_SPLIT, (float)xih1.h[u]);
    }
    const _Float16* xb = xhi + (size_t)b * NN * DD;

    float p = 0.0f;
    #pragma unroll
    for (int u = 0; u < 8; ++u) {
        p = fmaf((float)yh0.h[u], xi[u], p);
        p = fmaf((float)yh1.h[u], xi[8 + u], p);
    }
    p += __shfl_xor(p, 1); p += __shfl_xor(p, 2);
    p += __shfl_xor(p, 4); p += __shfl_xor(p, 8);
    float wd = (g == 0) ? (__expf(p) + 1e-5f) * adiag[row] : 0.0f;
    float denom = wd;
    float acc[16];
    #pragma unroll
    for (int u = 0; u < 16; ++u) acc[u] = wd * xi[u];

    const int c = cnt[row];
    const int* ip = idx + (size_t)row * MAXNZ;
    const int iters = (c + 7) >> 3;

    int jA1, jB1;
    H8 vA0, vA1, vB0, vB1;
    {
        int ja = (g < c) ? ip[g] : 0;
        int jb = (4 + g < c) ? ip[4 + g] : 0;
        jA1 = (8 + g < c) ? ip[8 + g] : 0;
        jB1 = (12 + g < c) ? ip[12 + g] : 0;
        const _Float16* pa = xb + (size_t)ja * DD + s * 8;
        vA0.i4 = *(const int4*)pa;
        vA1.i4 = *(const int4*)(pa + 128);
        const _Float16* pb = xb + (size_t)jb * DD + s * 8;
        vB0.i4 = *(const int4*)pb;
        vB1.i4 = *(const int4*)(pb + 128);
    }

    for (int t = 0; t < iters; ++t) {
        int k2a = (t + 2) * 8 + g;
        int k2b = k2a + 4;
        int jA2 = (k2a < c) ? ip[k2a] : 0;
        int jB2 = (k2b < c) ? ip[k2b] : 0;
        H8 mA0, mA1, mB0, mB1;
        const _Float16* pa = xb + (size_t)jA1 * DD + s * 8;
        mA0.i4 = *(const int4*)pa;
        mA1.i4 = *(const int4*)(pa + 128);
        const _Float16* pb = xb + (size_t)jB1 * DD + s * 8;
        mB0.i4 = *(const int4*)pb;
        mB1.i4 = *(const int4*)(pb + 128);

        bool vokA = t * 8 + g < c;
        bool vokB = t * 8 + 4 + g < c;

        float qa0 = 0.0f, qa1 = 0.0f, qb0 = 0.0f, qb1 = 0.0f;
        #pragma unroll
        for (int i = 0; i < 4; ++i) {
            qa0 = dot2f(yh0.p[i], vA0.p[i], qa0);
            qa1 = dot2f(yh1.p[i], vA1.p[i], qa1);
            qb0 = dot2f(yh0.p[i], vB0.p[i], qb0);
            qb1 = dot2f(yh1.p[i], vB1.p[i], qb1);
        }
        float qa = qa0 + qa1, qb = qb0 + qb1;
        qa += __shfl_xor(qa, 1); qb += __shfl_xor(qb, 1);
        qa += __shfl_xor(qa, 2); qb += __shfl_xor(qb, 2);
        qa += __shfl_xor(qa, 4); qb += __shfl_xor(qb, 4);
        qa += __shfl_xor(qa, 8); qb += __shfl_xor(qb, 8);
        float wa = vokA ? __expf(qa) : 0.0f;
        float wb = vokB ? __expf(qb) : 0.0f;
        denom += wa + wb;
        #pragma unroll
        for (int i = 0; i < 4; ++i) {
            fmix2(acc[2 * i],     acc[2 * i + 1],     vA0.w[i], wa);
            fmix2(acc[8 + 2 * i], acc[8 + 2 * i + 1], vA1.w[i], wa);
        }
        #pragma unroll
        for (int i = 0; i < 4; ++i) {
            fmix2(acc[2 * i],     acc[2 * i + 1],     vB0.w[i], wb);
            fmix2(acc[8 + 2 * i], acc[8 + 2 * i + 1], vB1.w[i], wb);
        }

        vA0 = mA0; vA1 = mA1; vB0 = mB0; vB1 = mB1;
        jA1 = jA2; jB1 = jB2;
    }

#define XG(x) x += __shfl_xor(x, 16); x += __shfl_xor(x, 32);
    XG(denom);
    #pragma unroll
    for (int u = 0; u < 16; ++u) { XG(acc[u]) }
#undef XG

    float inv = 1.0f / denom;
    int half = (g & 1) * 8;
    H8 st;
    #pragma unroll
    for (int i = 0; i < 8; ++i) {
        float x = acc[half + i] * inv;
        _Float16 h = (_Float16)x;
        st.h[i] = (g & 2) ? (_Float16)((x - (float)h) * SPLIT_SCALE) : h;
    }
    _Float16* dst = ((g & 2) ? olo : ohi) + (size_t)row * DD + (g & 1) * 128 + s * 8;
    *(int4*)dst = st.i4;
}

// ---------------------------------------------------------------------------
// Kernel 3: split-fp16 MFMA GEMM v8 (round-12, frozen) — used for y and final.
// ---------------------------------------------------------------------------
__global__ __launch_bounds__(512, 4) void gemm16(
    const _Float16* __restrict__ Ahi, const _Float16* __restrict__ Alo,
    const _Float16* __restrict__ Bhi, const _Float16* __restrict__ Blo,
    const float* __restrict__ bias,
    const _Float16* __restrict__ Shi, const _Float16* __restrict__ Slo,
    _Float16* __restrict__ Chi, _Float16* __restrict__ Clo,
    float* __restrict__ Cf32, int relu, int lo_write)
{
    __shared__ __align__(16) char smem[49152];
    char* Ah = smem;
    char* Al = smem + 16384;
    char* Bh = smem + 32768;
    char* Bl = smem + 40960;

    int tid = threadIdx.x;
    int mBase = blockIdx.y * 128;
    int nBase = blockIdx.x * 64;

    int ra = tid >> 2, ka = (tid & 3) * 16;
    const _Float16* gAh = Ahi + (size_t)(mBase + ra) * 256 + ka;
    const _Float16* gAl = Alo + (size_t)(mBase + ra) * 256 + ka;
    int sbA = ra * 128 + ka * 2, swzA = (ra & 7) << 4;
    int rb = tid >> 3, kbb = (tid & 7) * 8;
    const _Float16* gBh = Bhi + (size_t)(nBase + rb) * 256 + kbb;
    const _Float16* gBl = Blo + (size_t)(nBase + rb) * 256 + kbb;
    int sbB = rb * 128 + kbb * 2, swzB = (rb & 7) << 4;

    int l = tid & 63, wv = tid >> 6;
    int wm = (wv & 3) * 32, wn = (wv >> 2) * 32;
    int lr = l & 15, lk = l >> 4;

    f32x4 acc0[2][2] = {};
    f32x4 acc1[2][2] = {};

    int4 rA0, rA1, rA2, rA3, rB0, rB1;
#define LOADG(kb) \
    rA0 = *(const int4*)(gAh + (kb));     rA1 = *(const int4*)(gAh + (kb) + 8); \
    rA2 = *(const int4*)(gAl + (kb));     rA3 = *(const int4*)(gAl + (kb) + 8); \
    rB0 = *(const int4*)(gBh + (kb));     rB1 = *(const int4*)(gBl + (kb));

    LOADG(0)

    #pragma unroll
    for (int kb = 0; kb < 256; kb += 64) {
        __syncthreads();
        *(int4*)(Ah + ((sbA +  0) ^ swzA)) = rA0;
        *(int4*)(Ah + ((sbA + 16) ^ swzA)) = rA1;
        *(int4*)(Al + ((sbA +  0) ^ swzA)) = rA2;
        *(int4*)(Al + ((sbA + 16) ^ swzA)) = rA3;
        *(int4*)(Bh + (sbB ^ swzB)) = rB0;
        *(int4*)(Bl + (sbB ^ swzB)) = rB1;
        __syncthreads();

        if (kb < 192) { LOADG(kb + 64) }

        #pragma unroll
        for (int kk = 0; kk < 2; ++kk) {
            int kby = kk * 64 + lk * 16;
            f16x8 fah[2], fal[2], fbh[2], fbl[2];
            #pragma unroll
            for (int mt = 0; mt < 2; ++mt) {
                int ml = wm + mt * 16 + lr;
                int off = (ml * 128 + kby) ^ ((ml & 7) << 4);
                fah[mt] = *(const f16x8*)(Ah + off);
                fal[mt] = *(const f16x8*)(Al + off);
            }
            #pragma unroll
            for (int nt = 0; nt < 2; ++nt) {
                int nl = wn + nt * 16 + lr;
                int off = (nl * 128 + kby) ^ ((nl & 7) << 4);
                fbh[nt] = *(const f16x8*)(Bh + off);
                fbl[nt] = *(const f16x8*)(Bl + off);
            }
            #pragma unroll
            for (int mt = 0; mt < 2; ++mt)
                #pragma unroll
                for (int nt = 0; nt < 2; ++nt) {
                    acc0[mt][nt] = __builtin_amdgcn_mfma_f32_16x16x32_f16(
                        fah[mt], fbh[nt], acc0[mt][nt], 0, 0, 0);
                    acc1[mt][nt] = __builtin_amdgcn_mfma_f32_16x16x32_f16(
                        fah[mt], fbl[nt], acc1[mt][nt], 0, 0, 0);
                    acc1[mt][nt] = __builtin_amdgcn_mfma_f32_16x16x32_f16(
                        fal[mt], fbh[nt], acc1[mt][nt], 0, 0, 0);
                }
        }
    }
#undef LOADG

    __syncthreads();
    float* T = (float*)smem;
    #pragma unroll
    for (int mt = 0; mt < 2; ++mt)
        #pragma unroll
        for (int nt = 0; nt < 2; ++nt)
            #pragma unroll
            for (int q = 0; q < 4; ++q) {
                int m = wm + mt * 16 + lk * 4 + q;
                int n = wn + nt * 16 + lr;
                T[m * 68 + n] = acc0[mt][nt][q] + acc1[mt][nt][q] * INV_SPLIT;
            }
    __syncthreads();

    {
        int rr = tid >> 2;
        int c0 = (tid & 3) * 16;
        int m = mBase + rr;
        size_t o = (size_t)m * 256 + nBase + c0;
        float v[16];
        #pragma unroll
        for (int i = 0; i < 4; ++i) {
            float4 f = *(const float4*)&T[rr * 68 + c0 + i * 4];
            v[i * 4 + 0] = f.x; v[i * 4 + 1] = f.y;
            v[i * 4 + 2] = f.z; v[i * 4 + 3] = f.w;
        }
        if (bias) {
            #pragma unroll
            for (int i = 0; i < 4; ++i) {
                float4 bv = *(const float4*)(bias + nBase + c0 + i * 4);
                v[i * 4 + 0] += bv.x; v[i * 4 + 1] += bv.y;
                v[i * 4 + 2] += bv.z; v[i * 4 + 3] += bv.w;
            }
        }
        if (relu) {
            #pragma unroll
            for (int i = 0; i < 16; ++i) v[i] = fmaxf(v[i], 0.0f);
        }
        if (Shi) {
            #pragma unroll
            for (int j = 0; j < 2; ++j) {
                H8 sh, sl;
                sh.i4 = *(const int4*)(Shi + o + j * 8);
                sl.i4 = *(const int4*)(Slo + o + j * 8);
                #pragma unroll
                for (int u = 0; u < 8; ++u)
                    v[j * 8 + u] += fmaf((float)sl.h[u], INV_SPLIT, (float)sh.h[u]);
            }
        }
        if (Cf32) {
            #pragma unroll
            for (int i = 0; i < 4; ++i) {
                *(float4*)(Cf32 + o + i * 4) =
                    make_float4(v[i * 4], v[i * 4 + 1], v[i * 4 + 2], v[i * 4 + 3]);
            }
        } else {
            #pragma unroll
            for (int j = 0; j < 2; ++j) {
                H8 hh;
                #pragma unroll
                for (int u = 0; u < 8; ++u) hh.h[u] = (_Float16)v[j * 8 + u];
                *(int4*)(Chi + o + j * 8) = hh.i4;
            }
            if (lo_write) {
                #pragma unroll
                for (int j = 0; j < 2; ++j) {
                    H8 ll;
                    #pragma unroll
                    for (int u = 0; u < 8; ++u) {
                        float x = v[j * 8 + u];
                        ll.h[u] = (_Float16)((x - (float)(_Float16)x) * SPLIT_SCALE);
                    }
                    *(int4*)(Clo + o + j * 8) = ll.i4;
                }
            }
        }
    }
}

// ---------------------------------------------------------------------------
// Kernel 4: fused 2-layer MLP.  C = relu(relu(A@W1+b1)@W2+b2) + skip.
// BM=64, BN=256 (full width): H1 (64x256, hi/lo fp16) lives in LDS only.
// 512 threads = 8 waves (2m x 4n), wave tile 32x64 for both GEMMs.
// LDS: A-chunk 16K + W-panel 64K + H1 64K = 144 KB -> 1 block/CU, 250 blocks.
// ---------------------------------------------------------------------------
__global__ __launch_bounds__(512, 1) void mlp2(
    const _Float16* __restrict__ Ahi, const _Float16* __restrict__ Alo,
    const _Float16* __restrict__ W1h, const _Float16* __restrict__ W1l,
    const float* __restrict__ b1,
    const _Float16* __restrict__ W2h, const _Float16* __restrict__ W2l,
    const float* __restrict__ b2,
    const _Float16* __restrict__ Shi, const _Float16* __restrict__ Slo,
    _Float16* __restrict__ Chi, _Float16* __restrict__ Clo)
{
    __shared__ __align__(16) char smem[147456];
    char* As  = smem;                 // [64 m][64 k] hi, 8 KB
    char* Asl = smem + 8192;          // lo
    char* Wp  = smem + 16384;         // [256 n][64 k] hi, 32 KB
    char* Wpl = smem + 49152;         // lo
    char* H1h = smem + 81920;         // [64 m][256 k] hi, 32 KB
    char* H1l = smem + 114688;        // lo

    int tid = threadIdx.x;
    int mBase = blockIdx.x * 64;

    int ra = tid >> 3, ka = (tid & 7) * 8;     // A staging: row, k-halves
    const _Float16* gAh = Ahi + (size_t)(mBase + ra) * 256 + ka;
    const _Float16* gAl = Alo + (size_t)(mBase + ra) * 256 + ka;
    int sbA = ra * 128 + ka * 2, swA = (ra & 7) << 4;

    int rw = tid >> 1, kw = (tid & 1) * 32;    // W staging: row, k-halves
    int sbW = rw * 128 + kw * 2, swW = (rw & 7) << 4;

    int l = tid & 63, wv = tid >> 6;
    int wm = (wv & 1) * 32, wn = (wv >> 1) * 64;
    int lr = l & 15, lk = l >> 4;

    f32x4 acc0[2][4] = {};
    f32x4 acc1[2][4] = {};

    int4 pA0, pA1, pW[8];
#define LA(kb) { pA0 = *(const int4*)(gAh + (kb)); pA1 = *(const int4*)(gAl + (kb)); }
#define LW(Wh, Wl, kb) { \
    const _Float16* _wh = (Wh) + (size_t)rw * 256 + kw + (kb); \
    const _Float16* _wl = (Wl) + (size_t)rw * 256 + kw + (kb); \
    pW[0] = *(const int4*)(_wh);      pW[1] = *(const int4*)(_wh + 8);  \
    pW[2] = *(const int4*)(_wh + 16); pW[3] = *(const int4*)(_wh + 24); \
    pW[4] = *(const int4*)(_wl);      pW[5] = *(const int4*)(_wl + 8);  \
    pW[6] = *(const int4*)(_wl + 16); pW[7] = *(const int4*)(_wl + 24); }
#define STW() \
    *(int4*)(Wp  + ((sbW +  0) ^ swW)) = pW[0]; \
    *(int4*)(Wp  + ((sbW + 16) ^ swW)) = pW[1]; \
    *(int4*)(Wp  + ((sbW + 32) ^ swW)) = pW[2]; \
    *(int4*)(Wp  + ((sbW + 48) ^ swW)) = pW[3]; \
    *(int4*)(Wpl + ((sbW +  0) ^ swW)) = pW[4]; \
    *(int4*)(Wpl + ((sbW + 16) ^ swW)) = pW[5]; \
    *(int4*)(Wpl + ((sbW + 32) ^ swW)) = pW[6]; \
    *(int4*)(Wpl + ((sbW + 48) ^ swW)) = pW[7];
// one K-chunk of MFMAs; A-frags from (base, rowStrideBytes, kOffBytes)
#define COMPUTE(ABASE_H, ABASE_L, RSTR, KOFF) \
    _Pragma("unroll") \
    for (int kk = 0; kk < 2; ++kk) { \
        int kby = kk * 64 + lk * 16; \
        f16x8 fah[2], fal[2], fbh[4], fbl[4]; \
        _Pragma("unroll") \
        for (int mt = 0; mt < 2; ++mt) { \
            int ml = wm + mt * 16 + lr; \
            int off = (ml * (RSTR) + (KOFF) + kby) ^ ((ml & 7) << 4); \
            fah[mt] = *(const f16x8*)((ABASE_H) + off); \
            fal[mt] = *(const f16x8*)((ABASE_L) + off); \
        } \
        _Pragma("unroll") \
        for (int nt = 0; nt < 4; ++nt) { \
            int nl = wn + nt * 16 + lr; \
            int off = (nl * 128 + kby) ^ ((nl & 7) << 4); \
            fbh[nt] = *(const f16x8*)(Wp + off); \
            fbl[nt] = *(const f16x8*)(Wpl + off); \
        } \
        _Pragma("unroll") \
        for (int mt = 0; mt < 2; ++mt) \
            _Pragma("unroll") \
            for (int nt = 0; nt < 4; ++nt) { \
                acc0[mt][nt] = __builtin_amdgcn_mfma_f32_16x16x32_f16( \
                    fah[mt], fbh[nt], acc0[mt][nt], 0, 0, 0); \
                acc1[mt][nt] = __builtin_amdgcn_mfma_f32_16x16x32_f16( \
                    fah[mt], fbl[nt], acc1[mt][nt], 0, 0, 0); \
                acc1[mt][nt] = __builtin_amdgcn_mfma_f32_16x16x32_f16( \
                    fal[mt], fbh[nt], acc1[mt][nt], 0, 0, 0); \
            } \
    }

    // ---------------- GEMM1: H1 = relu(A @ W1 + b1) ----------------
    LA(0) LW(W1h, W1l, 0)
    #pragma unroll
    for (int kb = 0; kb < 256; kb += 64) {
        __syncthreads();
        *(int4*)(As  + (sbA ^ swA)) = pA0;
        *(int4*)(Asl + (sbA ^ swA)) = pA1;
        STW()
        __syncthreads();
        if (kb < 192) { LA(kb + 64) LW(W1h, W1l, kb + 64) }
        COMPUTE(As, Asl, 128, 0)
    }

    // epilogue 1: bias + relu + split -> H1 in LDS
    {
        #pragma unroll
        for (int mt = 0; mt < 2; ++mt)
            #pragma unroll
            for (int nt = 0; nt < 4; ++nt) {
                int n = wn + nt * 16 + lr;
                float bv = b1[n];
                #pragma unroll
                for (int q = 0; q < 4; ++q) {
                    int m = wm + mt * 16 + lk * 4 + q;
                    float v = acc0[mt][nt][q] + acc1[mt][nt][q] * INV_SPLIT + bv;
                    v = fmaxf(v, 0.0f);
                    _Float16 h = (_Float16)v;
                    int off = (m * 512 + n * 2) ^ ((m & 7) << 4);
                    *(_Float16*)(H1h + off) = h;
                    *(_Float16*)(H1l + off) = (_Float16)((v - (float)h) * SPLIT_SCALE);
                }
                #pragma unroll
                for (int q = 0; q < 4; ++q) {
                    acc0[mt][nt][q] = 0.0f;
                    acc1[mt][nt][q] = 0.0f;
                }
            }
    }

    // ---------------- GEMM2: C = relu(H1 @ W2 + b2) + skip ----------------
    LW(W2h, W2l, 0)
    #pragma unroll
    for (int kb = 0; kb < 256; kb += 64) {
        __syncthreads();   // also guards H1 writes (first iter) / Wp reuse
        STW()
        __syncthreads();
        if (kb < 192) { LW(W2h, W2l, kb + 64) }
        COMPUTE(H1h, H1l, 512, kb * 2)
    }

    // epilogue 2: bias + relu + skip + split -> global
    #pragma unroll
    for (int mt = 0; mt < 2; ++mt)
        #pragma unroll
        for (int nt = 0; nt < 4; ++nt) {
            int n = wn + nt * 16 + lr;
            float bv = b2[n];
            #pragma unroll
            for (int q = 0; q < 4; ++q) {
                int m = mBase + wm + mt * 16 + lk * 4 + q;
                size_t o = (size_t)m * 256 + n;
                float v = acc0[mt][nt][q] + acc1[mt][nt][q] * INV_SPLIT + bv;
                v = fmaxf(v, 0.0f);
                v += fmaf((float)Slo[o], INV_SPLIT, (float)Shi[o]);
                _Float16 h = (_Float16)v;
                Chi[o] = h;
                Clo[o] = (_Float16)((v - (float)h) * SPLIT_SCALE);
            }
        }
#undef LA
#undef LW
#undef STW
#undef COMPUTE
}

// ---------------------------------------------------------------------------
extern "C" void kernel_launch(void* const* d_in, const int* in_sizes, int n_in,
                              void* d_out, int out_size, void* d_ws, size_t ws_size,
                              hipStream_t stream)
{
    const float* x_in     = (const float*)d_in[0];
    const float* contacts = (const float*)d_in[1];
    const float* W_list   = (const float*)d_in[2];
    const float* dense_W  = (const float*)d_in[3];
    const float* dense_b  = (const float*)d_in[4];
    const float* final_W  = (const float*)d_in[5];
    const float* final_b  = (const float*)d_in[6];
    float* out = (float*)d_out;

    char* ws = (char*)d_ws;
    const size_t PL = (size_t)MROWS * DD;
    _Float16* pl[8];
    for (int i = 0; i < 8; ++i) pl[i] = (_Float16*)ws + (size_t)i * PL;
    char* p8 = ws + 8 * PL * sizeof(_Float16);
    int*   idx   = (int*)p8;
    int*   cnt   = (int*)(p8 + (size_t)MROWS * MAXNZ * sizeof(int));
    float* adiag = (float*)((char*)cnt + (size_t)MROWS * sizeof(int));
    _Float16* wt_hi = (_Float16*)((char*)adiag + (size_t)MROWS * sizeof(float));
    _Float16* wt_lo = wt_hi + (size_t)10 * 65536;

    setup_all<<<6160, 256, 0, stream>>>(W_list, dense_W, final_W, wt_hi, wt_lo,
                                        x_in, pl[0], pl[1],
                                        contacts, idx, cnt, adiag);

    dim3 gg(4, MROWS / 128);   // (4, 125) for gemm16
    int cur = 0;
    for (int l = 0; l < LL; ++l) {
        int oth = 1 - cur;
        _Float16 *x0h = pl[2 * cur], *x0l = pl[2 * cur + 1];
        _Float16 *yh  = pl[2 * oth], *yl  = pl[2 * oth + 1];
        _Float16 *xah = pl[4], *xal = pl[5];
        // y = x0 @ W_l (hi out only — scores tolerate fp16)
        gemm16<<<gg, 512, 0, stream>>>(x0h, x0l,
                                       wt_hi + (size_t)l * 65536,
                                       wt_lo + (size_t)l * 65536,
                                       nullptr, nullptr, nullptr,
                                       yh, yl, nullptr, 0, 0);
        // sparse attention aggregate
        sparse_agg<<<MROWS / 4, 256, 0, stream>>>(yh, x0h, x0l, idx, cnt, adiag,
                                                  xah, xal);
        // fused dense1+dense2(+skip) -> next X0
        mlp2<<<MROWS / 64, 512, 0, stream>>>(xah, xal,
                                             wt_hi + (size_t)(3 + l * 2) * 65536,
                                             wt_lo + (size_t)(3 + l * 2) * 65536,
                                             dense_b + (size_t)(l * 2 + 0) * 256,
                                             wt_hi + (size_t)(4 + l * 2) * 65536,
                                             wt_lo + (size_t)(4 + l * 2) * 65536,
                                             dense_b + (size_t)(l * 2 + 1) * 256,
                                             x0h, x0l,
                                             yh, yl);
        cur = oth;
    }
    // final projection -> fp32 d_out
    gemm16<<<gg, 512, 0, stream>>>(pl[2 * cur], pl[2 * cur + 1],
                                   wt_hi + (size_t)9 * 65536,
                                   wt_lo + (size_t)9 * 65536,
                                   final_b, nullptr, nullptr,
                                   nullptr, nullptr, out, 0, 0);
}

// Round 16
// 268.070 us; speedup vs baseline: 1.2000x; 1.2000x over previous
//
#include <hip/hip_runtime.h>

#define BB 16
#define NN 1000
#define DD 256
#define LL 3
#define MAXNZ 256
#define MROWS (BB * NN)
#define SPLIT_SCALE 2048.0f
#define INV_SPLIT 4.8828125e-4f

typedef _Float16 f16x8 __attribute__((ext_vector_type(8)));
typedef _Float16 f16x2 __attribute__((ext_vector_type(2)));
typedef float f32x4 __attribute__((ext_vector_type(4)));

union H8 { f16x8 v; f16x2 p[4]; _Float16 h[8]; int4 i4; unsigned int w[4]; };

#if defined(__has_builtin)
#if __has_builtin(__builtin_amdgcn_fdot2)
#define HAS_FDOT2 1
#endif
#endif

__device__ __forceinline__ float dot2f(f16x2 a, f16x2 b, float c) {
#ifdef HAS_FDOT2
    return __builtin_amdgcn_fdot2(a, b, c, false);
#else
    return fmaf((float)a[0], (float)b[0], fmaf((float)a[1], (float)b[1], c));
#endif
}

__device__ __forceinline__ void fmix2(float& alo, float& ahi,
                                      unsigned int pk, float s) {
    asm("v_fma_mix_f32 %0, %1, %2, %0 op_sel:[0,0,0] op_sel_hi:[1,0,0]"
        : "+v"(alo) : "v"(pk), "v"(s));
    asm("v_fma_mix_f32 %0, %1, %2, %0 op_sel:[1,0,0] op_sel_hi:[1,0,0]"
        : "+v"(ahi) : "v"(pk), "v"(s));
}

// 16-lane allreduce on the VALU: rotate-add via DPP row_ror (row = 16 lanes
// on CDNA). ctrl row_ror:N = 0x120+N — must be a compile-time constant, so
// it's a template parameter.
template <int CTRL>
__device__ __forceinline__ float rot_add(float x) {
    int t = __builtin_amdgcn_update_dpp(0, __builtin_bit_cast(int, x),
                                        CTRL, 0xf, 0xf, false);
    return x + __builtin_bit_cast(float, t);
}
__device__ __forceinline__ float reduce16(float q) {
    q = rot_add<0x121>(q);   // row_ror:1
    q = rot_add<0x122>(q);   // row_ror:2
    q = rot_add<0x124>(q);   // row_ror:4
    q = rot_add<0x128>(q);   // row_ror:8
    return q;
}

// ---------------------------------------------------------------------------
// Kernel 0 (fused setup): [0,160) convert_w, [160,2160) convert_x,
// [2160,6160) build_sparse.
// ---------------------------------------------------------------------------
__global__ __launch_bounds__(256) void setup_all(
    const float* __restrict__ W_list, const float* __restrict__ dense_W,
    const float* __restrict__ final_W,
    _Float16* __restrict__ wt_hi, _Float16* __restrict__ wt_lo,
    const float* __restrict__ x_in,
    _Float16* __restrict__ xh, _Float16* __restrict__ xl,
    const float* __restrict__ contacts,
    int* __restrict__ idx, int* __restrict__ cnt, float* __restrict__ adiag)
{
    __shared__ float T[64][68];
    int bid = blockIdx.x;
    int t = threadIdx.x;

    if (bid < 160) {
        int mat = bid >> 4;
        int tile = bid & 15;
        int tk = (tile >> 2) * 64, tn = (tile & 3) * 64;
        const float* src = (mat < 3) ? (W_list + (size_t)mat * 65536)
                         : (mat < 9) ? (dense_W + (size_t)(mat - 3) * 65536)
                                     : final_W;
        {
            int k = t >> 2, nc = (t & 3) * 16;
            const float* sp = src + (size_t)(tk + k) * 256 + tn + nc;
            *(float4*)&T[k][nc + 0]  = *(const float4*)(sp + 0);
            *(float4*)&T[k][nc + 4]  = *(const float4*)(sp + 4);
            *(float4*)&T[k][nc + 8]  = *(const float4*)(sp + 8);
            *(float4*)&T[k][nc + 12] = *(const float4*)(sp + 12);
        }
        __syncthreads();
        int n = t >> 2, kc = (t & 3) * 16;
        H8 hh0, hh1, ll0, ll1;
        #pragma unroll
        for (int i = 0; i < 16; ++i) {
            float x = T[kc + i][n];
            _Float16 hi = (_Float16)x;
            _Float16 lo = (_Float16)((x - (float)hi) * SPLIT_SCALE);
            if (i < 8) { hh0.h[i] = hi; ll0.h[i] = lo; }
            else       { hh1.h[i - 8] = hi; ll1.h[i - 8] = lo; }
        }
        size_t o = (size_t)mat * 65536 + (size_t)(tn + n) * 256 + tk + kc;
        *(int4*)(wt_hi + o)     = hh0.i4;
        *(int4*)(wt_hi + o + 8) = hh1.i4;
        *(int4*)(wt_lo + o)     = ll0.i4;
        *(int4*)(wt_lo + o + 8) = ll1.i4;
    } else if (bid < 2160) {
        size_t gid = (size_t)(bid - 160) * 256 + t;
        const float* p = x_in + gid * 8;
        float4 a = *(const float4*)p;
        float4 b = *(const float4*)(p + 4);
        float xs[8] = {a.x, a.y, a.z, a.w, b.x, b.y, b.z, b.w};
        H8 hh, ll;
        #pragma unroll
        for (int i = 0; i < 8; ++i) {
            _Float16 h = (_Float16)xs[i];
            hh.h[i] = h;
            ll.h[i] = (_Float16)((xs[i] - (float)h) * SPLIT_SCALE);
        }
        *(int4*)(xh + gid * 8) = hh.i4;
        *(int4*)(xl + gid * 8) = ll.i4;
    } else {
        int wave = (int)(((size_t)(bid - 2160) * 256 + t) >> 6);
        int lane = t & 63;
        int b = wave / NN;
        int i = wave - b * NN;
        const float* row = contacts + (size_t)b * NN * NN + (size_t)i * NN;
        int* out = idx + (size_t)wave * MAXNZ;
        int count = 0;
        for (int j0 = 0; j0 < NN; j0 += 64) {
            int j = j0 + lane;
            float v = (j < NN) ? row[j] : 0.0f;
            bool p = (v != 0.0f) && (j != i);
            unsigned long long bal = __ballot(p);
            if (p) {
                int pre = __popcll(bal & ((1ull << lane) - 1ull));
                out[count + pre] = j;
            }
            count += __popcll(bal);
        }
        if (lane == 0) {
            cnt[wave] = count;
            adiag[wave] = row[i] + 1.0f;
        }
    }
}

// ---------------------------------------------------------------------------
// Kernel 2: sparse attention aggregate v9 = v8 with DPP rotate-add reduce
// (replaces the 4-level DS shfl_xor chain per q with 4 VALU DPP steps).
// ---------------------------------------------------------------------------
__global__ __launch_bounds__(256, 3) void sparse_agg(
    const _Float16* __restrict__ yhi,
    const _Float16* __restrict__ xhi, const _Float16* __restrict__ xlo,
    const int* __restrict__ idx, const int* __restrict__ cnt,
    const float* __restrict__ adiag,
    _Float16* __restrict__ ohi, _Float16* __restrict__ olo)
{
    int bid = blockIdx.x;
    int xcd = bid & 7;
    int chunk = bid >> 3;
    int row = xcd * 2000 + chunk * 4 + (int)(threadIdx.x >> 6);
    row = __builtin_amdgcn_readfirstlane(row);
    int lane = threadIdx.x & 63;
    int g = lane >> 4, s = lane & 15;
    int b = row / NN;

    const _Float16* yp = yhi + (size_t)row * DD + s * 8;
    H8 yh0, yh1;
    yh0.i4 = *(const int4*)yp;
    yh1.i4 = *(const int4*)(yp + 128);

    const _Float16* xph = xhi + (size_t)row * DD + s * 8;
    const _Float16* xpl = xlo + (size_t)row * DD + s * 8;
    H8 xih0, xih1, xil0, xil1;
    xih0.i4 = *(const int4*)xph;       xih1.i4 = *(const int4*)(xph + 128);
    xil0.i4 = *(const int4*)xpl;       xil1.i4 = *(const int4*)(xpl + 128);
    float xi[16];
    #pragma unroll
    for (int u = 0; u < 8; ++u) {
        xi[u]     = fmaf((float)xil0.h[u], INV_SPLIT, (float)xih0.h[u]);
        xi[8 + u] = fmaf((float)xil1.h[u], INV_SPLIT, (float)xih1.h[u]);
    }
    const _Float16* xb = xhi + (size_t)b * NN * DD;

    float p = 0.0f;
    #pragma unroll
    for (int u = 0; u < 8; ++u) {
        p = fmaf((float)yh0.h[u], xi[u], p);
        p = fmaf((float)yh1.h[u], xi[8 + u], p);
    }
    p = reduce16(p);
    float wd = (g == 0) ? (__expf(p) + 1e-5f) * adiag[row] : 0.0f;
    float denom = wd;
    float acc[16];
    #pragma unroll
    for (int u = 0; u < 16; ++u) acc[u] = wd * xi[u];

    const int c = cnt[row];
    const int* ip = idx + (size_t)row * MAXNZ;
    const int iters = (c + 7) >> 3;

    int jA1, jB1;
    H8 vA0, vA1, vB0, vB1;
    {
        int ja = (g < c) ? ip[g] : 0;
        int jb = (4 + g < c) ? ip[4 + g] : 0;
        jA1 = (8 + g < c) ? ip[8 + g] : 0;
        jB1 = (12 + g < c) ? ip[12 + g] : 0;
        const _Float16* pa = xb + (size_t)ja * DD + s * 8;
        vA0.i4 = *(const int4*)pa;
        vA1.i4 = *(const int4*)(pa + 128);
        const _Float16* pb = xb + (size_t)jb * DD + s * 8;
        vB0.i4 = *(const int4*)pb;
        vB1.i4 = *(const int4*)(pb + 128);
    }

    for (int t = 0; t < iters; ++t) {
        int k2a = (t + 2) * 8 + g;
        int k2b = k2a + 4;
        int jA2 = (k2a < c) ? ip[k2a] : 0;
        int jB2 = (k2b < c) ? ip[k2b] : 0;
        H8 mA0, mA1, mB0, mB1;
        const _Float16* pa = xb + (size_t)jA1 * DD + s * 8;
        mA0.i4 = *(const int4*)pa;
        mA1.i4 = *(const int4*)(pa + 128);
        const _Float16* pb = xb + (size_t)jB1 * DD + s * 8;
        mB0.i4 = *(const int4*)pb;
        mB1.i4 = *(const int4*)(pb + 128);

        bool vokA = t * 8 + g < c;
        bool vokB = t * 8 + 4 + g < c;

        float qa0 = 0.0f, qa1 = 0.0f, qb0 = 0.0f, qb1 = 0.0f;
        #pragma unroll
        for (int i = 0; i < 4; ++i) {
            qa0 = dot2f(yh0.p[i], vA0.p[i], qa0);
            qa1 = dot2f(yh1.p[i], vA1.p[i], qa1);
            qb0 = dot2f(yh0.p[i], vB0.p[i], qb0);
            qb1 = dot2f(yh1.p[i], vB1.p[i], qb1);
        }
        float qa = reduce16(qa0 + qa1);
        float qb = reduce16(qb0 + qb1);
        float wa = vokA ? __expf(qa) : 0.0f;
        float wb = vokB ? __expf(qb) : 0.0f;
        denom += wa + wb;
        #pragma unroll
        for (int i = 0; i < 4; ++i) {
            fmix2(acc[2 * i],     acc[2 * i + 1],     vA0.w[i], wa);
            fmix2(acc[8 + 2 * i], acc[8 + 2 * i + 1], vA1.w[i], wa);
        }
        #pragma unroll
        for (int i = 0; i < 4; ++i) {
            fmix2(acc[2 * i],     acc[2 * i + 1],     vB0.w[i], wb);
            fmix2(acc[8 + 2 * i], acc[8 + 2 * i + 1], vB1.w[i], wb);
        }

        vA0 = mA0; vA1 = mA1; vB0 = mB0; vB1 = mB1;
        jA1 = jA2; jB1 = jB2;
    }

#define XG(x) x += __shfl_xor(x, 16); x += __shfl_xor(x, 32);
    XG(denom);
    #pragma unroll
    for (int u = 0; u < 16; ++u) { XG(acc[u]) }
#undef XG

    float inv = 1.0f / denom;
    int half = (g & 1) * 8;
    H8 st;
    #pragma unroll
    for (int i = 0; i < 8; ++i) {
        float x = acc[half + i] * inv;
        _Float16 h = (_Float16)x;
        st.h[i] = (g & 2) ? (_Float16)((x - (float)h) * SPLIT_SCALE) : h;
    }
    _Float16* dst = ((g & 2) ? olo : ohi) + (size_t)row * DD + (g & 1) * 128 + s * 8;
    *(int4*)dst = st.i4;
}

// ---------------------------------------------------------------------------
// Kernel 3: split-fp16 MFMA GEMM v8 (round-12/13, frozen).
// BM=128, BN=64, BK=64; 512 threads = 8 waves (4m x 2n), wave tile 32x32.
// ---------------------------------------------------------------------------
__global__ __launch_bounds__(512, 4) void gemm16(
    const _Float16* __restrict__ Ahi, const _Float16* __restrict__ Alo,
    const _Float16* __restrict__ Bhi, const _Float16* __restrict__ Blo,
    const float* __restrict__ bias,
    const _Float16* __restrict__ Shi, const _Float16* __restrict__ Slo,
    _Float16* __restrict__ Chi, _Float16* __restrict__ Clo,
    float* __restrict__ Cf32, int relu, int lo_write)
{
    __shared__ __align__(16) char smem[49152];
    char* Ah = smem;
    char* Al = smem + 16384;
    char* Bh = smem + 32768;
    char* Bl = smem + 40960;

    int tid = threadIdx.x;
    int mBase = blockIdx.y * 128;
    int nBase = blockIdx.x * 64;

    int ra = tid >> 2, ka = (tid & 3) * 16;
    const _Float16* gAh = Ahi + (size_t)(mBase + ra) * 256 + ka;
    const _Float16* gAl = Alo + (size_t)(mBase + ra) * 256 + ka;
    int sbA = ra * 128 + ka * 2, swzA = (ra & 7) << 4;
    int rb = tid >> 3, kbb = (tid & 7) * 8;
    const _Float16* gBh = Bhi + (size_t)(nBase + rb) * 256 + kbb;
    const _Float16* gBl = Blo + (size_t)(nBase + rb) * 256 + kbb;
    int sbB = rb * 128 + kbb * 2, swzB = (rb & 7) << 4;

    int l = tid & 63, wv = tid >> 6;
    int wm = (wv & 3) * 32, wn = (wv >> 2) * 32;
    int lr = l & 15, lk = l >> 4;

    f32x4 acc0[2][2] = {};
    f32x4 acc1[2][2] = {};

    int4 rA0, rA1, rA2, rA3, rB0, rB1;
#define LOADG(kb) \
    rA0 = *(const int4*)(gAh + (kb));     rA1 = *(const int4*)(gAh + (kb) + 8); \
    rA2 = *(const int4*)(gAl + (kb));     rA3 = *(const int4*)(gAl + (kb) + 8); \
    rB0 = *(const int4*)(gBh + (kb));     rB1 = *(const int4*)(gBl + (kb));

    LOADG(0)

    #pragma unroll
    for (int kb = 0; kb < 256; kb += 64) {
        __syncthreads();
        *(int4*)(Ah + ((sbA +  0) ^ swzA)) = rA0;
        *(int4*)(Ah + ((sbA + 16) ^ swzA)) = rA1;
        *(int4*)(Al + ((sbA +  0) ^ swzA)) = rA2;
        *(int4*)(Al + ((sbA + 16) ^ swzA)) = rA3;
        *(int4*)(Bh + (sbB ^ swzB)) = rB0;
        *(int4*)(Bl + (sbB ^ swzB)) = rB1;
        __syncthreads();

        if (kb < 192) { LOADG(kb + 64) }

        #pragma unroll
        for (int kk = 0; kk < 2; ++kk) {
            int kby = kk * 64 + lk * 16;
            f16x8 fah[2], fal[2], fbh[2], fbl[2];
            #pragma unroll
            for (int mt = 0; mt < 2; ++mt) {
                int ml = wm + mt * 16 + lr;
                int off = (ml * 128 + kby) ^ ((ml & 7) << 4);
                fah[mt] = *(const f16x8*)(Ah + off);
                fal[mt] = *(const f16x8*)(Al + off);
            }
            #pragma unroll
            for (int nt = 0; nt < 2; ++nt) {
                int nl = wn + nt * 16 + lr;
                int off = (nl * 128 + kby) ^ ((nl & 7) << 4);
                fbh[nt] = *(const f16x8*)(Bh + off);
                fbl[nt] = *(const f16x8*)(Bl + off);
            }
            #pragma unroll
            for (int mt = 0; mt < 2; ++mt)
                #pragma unroll
                for (int nt = 0; nt < 2; ++nt) {
                    acc0[mt][nt] = __builtin_amdgcn_mfma_f32_16x16x32_f16(
                        fah[mt], fbh[nt], acc0[mt][nt], 0, 0, 0);
                    acc1[mt][nt] = __builtin_amdgcn_mfma_f32_16x16x32_f16(
                        fah[mt], fbl[nt], acc1[mt][nt], 0, 0, 0);
                    acc1[mt][nt] = __builtin_amdgcn_mfma_f32_16x16x32_f16(
                        fal[mt], fbh[nt], acc1[mt][nt], 0, 0, 0);
                }
        }
    }
#undef LOADG

    __syncthreads();
    float* T = (float*)smem;
    #pragma unroll
    for (int mt = 0; mt < 2; ++mt)
        #pragma unroll
        for (int nt = 0; nt < 2; ++nt)
            #pragma unroll
            for (int q = 0; q < 4; ++q) {
                int m = wm + mt * 16 + lk * 4 + q;
                int n = wn + nt * 16 + lr;
                T[m * 68 + n] = acc0[mt][nt][q] + acc1[mt][nt][q] * INV_SPLIT;
            }
    __syncthreads();

    {
        int rr = tid >> 2;
        int c0 = (tid & 3) * 16;
        int m = mBase + rr;
        size_t o = (size_t)m * 256 + nBase + c0;
        float v[16];
        #pragma unroll
        for (int i = 0; i < 4; ++i) {
            float4 f = *(const float4*)&T[rr * 68 + c0 + i * 4];
            v[i * 4 + 0] = f.x; v[i * 4 + 1] = f.y;
            v[i * 4 + 2] = f.z; v[i * 4 + 3] = f.w;
        }
        if (bias) {
            #pragma unroll
            for (int i = 0; i < 4; ++i) {
                float4 bv = *(const float4*)(bias + nBase + c0 + i * 4);
                v[i * 4 + 0] += bv.x; v[i * 4 + 1] += bv.y;
                v[i * 4 + 2] += bv.z; v[i * 4 + 3] += bv.w;
            }
        }
        if (relu) {
            #pragma unroll
            for (int i = 0; i < 16; ++i) v[i] = fmaxf(v[i], 0.0f);
        }
        if (Shi) {
            #pragma unroll
            for (int j = 0; j < 2; ++j) {
                H8 sh, sl;
                sh.i4 = *(const int4*)(Shi + o + j * 8);
                sl.i4 = *(const int4*)(Slo + o + j * 8);
                #pragma unroll
                for (int u = 0; u < 8; ++u)
                    v[j * 8 + u] += fmaf((float)sl.h[u], INV_SPLIT, (float)sh.h[u]);
            }
        }
        if (Cf32) {
            #pragma unroll
            for (int i = 0; i < 4; ++i) {
                *(float4*)(Cf32 + o + i * 4) =
                    make_float4(v[i * 4], v[i * 4 + 1], v[i * 4 + 2], v[i * 4 + 3]);
            }
        } else {
            #pragma unroll
            for (int j = 0; j < 2; ++j) {
                H8 hh;
                #pragma unroll
                for (int u = 0; u < 8; ++u) hh.h[u] = (_Float16)v[j * 8 + u];
                *(int4*)(Chi + o + j * 8) = hh.i4;
            }
            if (lo_write) {
                #pragma unroll
                for (int j = 0; j < 2; ++j) {
                    H8 ll;
                    #pragma unroll
                    for (int u = 0; u < 8; ++u) {
                        float x = v[j * 8 + u];
                        ll.h[u] = (_Float16)((x - (float)(_Float16)x) * SPLIT_SCALE);
                    }
                    *(int4*)(Clo + o + j * 8) = ll.i4;
                }
            }
        }
    }
}

// ---------------------------------------------------------------------------
extern "C" void kernel_launch(void* const* d_in, const int* in_sizes, int n_in,
                              void* d_out, int out_size, void* d_ws, size_t ws_size,
                              hipStream_t stream)
{
    const float* x_in     = (const float*)d_in[0];
    const float* contacts = (const float*)d_in[1];
    const float* W_list   = (const float*)d_in[2];
    const float* dense_W  = (const float*)d_in[3];
    const float* dense_b  = (const float*)d_in[4];
    const float* final_W  = (const float*)d_in[5];
    const float* final_b  = (const float*)d_in[6];
    float* out = (float*)d_out;

    char* ws = (char*)d_ws;
    const size_t PL = (size_t)MROWS * DD;
    _Float16* pl[8];
    for (int i = 0; i < 8; ++i) pl[i] = (_Float16*)ws + (size_t)i * PL;
    char* p8 = ws + 8 * PL * sizeof(_Float16);
    int*   idx   = (int*)p8;
    int*   cnt   = (int*)(p8 + (size_t)MROWS * MAXNZ * sizeof(int));
    float* adiag = (float*)((char*)cnt + (size_t)MROWS * sizeof(int));
    _Float16* wt_hi = (_Float16*)((char*)adiag + (size_t)MROWS * sizeof(float));
    _Float16* wt_lo = wt_hi + (size_t)10 * 65536;

    setup_all<<<6160, 256, 0, stream>>>(W_list, dense_W, final_W, wt_hi, wt_lo,
                                        x_in, pl[0], pl[1],
                                        contacts, idx, cnt, adiag);

    dim3 gg(4, MROWS / 128);   // (4, 125) = 500 blocks x 512 threads
    int cur = 0;
    for (int l = 0; l < LL; ++l) {
        int oth = 1 - cur;
        _Float16 *x0h = pl[2 * cur], *x0l = pl[2 * cur + 1];
        _Float16 *yh  = pl[2 * oth], *yl  = pl[2 * oth + 1];
        _Float16 *xah = pl[4], *xal = pl[5];
        _Float16 *xbh = pl[6], *xbl = pl[7];
        // y = x0 @ W_l (hi out only — scores tolerate fp16)
        gemm16<<<gg, 512, 0, stream>>>(x0h, x0l,
                                       wt_hi + (size_t)l * 65536,
                                       wt_lo + (size_t)l * 65536,
                                       nullptr, nullptr, nullptr,
                                       yh, yl, nullptr, 0, 0);
        // sparse attention aggregate
        sparse_agg<<<MROWS / 4, 256, 0, stream>>>(yh, x0h, x0l, idx, cnt, adiag,
                                                  xah, xal);
        // dense 1 (relu)
        gemm16<<<gg, 512, 0, stream>>>(xah, xal,
                                       wt_hi + (size_t)(3 + l * 2) * 65536,
                                       wt_lo + (size_t)(3 + l * 2) * 65536,
                                       dense_b + (size_t)(l * 2 + 0) * 256,
                                       nullptr, nullptr,
                                       xbh, xbl, nullptr, 1, 1);
        // dense 2 (relu) + skip(x0) -> next X0
        gemm16<<<gg, 512, 0, stream>>>(xbh, xbl,
                                       wt_hi + (size_t)(4 + l * 2) * 65536,
                                       wt_lo + (size_t)(4 + l * 2) * 65536,
                                       dense_b + (size_t)(l * 2 + 1) * 256,
                                       x0h, x0l,
                                       yh, yl, nullptr, 1, 1);
        cur = oth;
    }
    // final projection -> fp32 d_out
    gemm16<<<gg, 512, 0, stream>>>(pl[2 * cur], pl[2 * cur + 1],
                                   wt_hi + (size_t)9 * 65536,
                                   wt_lo + (size_t)9 * 65536,
                                   final_b, nullptr, nullptr,
                                   nullptr, nullptr, out, 0, 0);
}

// Round 17
// 257.860 us; speedup vs baseline: 1.2475x; 1.0396x over previous
//
#include <hip/hip_runtime.h>

#define BB 16
#define NN 1000
#define DD 256
#define LL 3
#define MAXNZ 256
#define MROWS (BB * NN)
#define SPLIT_SCALE 2048.0f
#define INV_SPLIT 4.8828125e-4f

typedef _Float16 f16x8 __attribute__((ext_vector_type(8)));
typedef _Float16 f16x2 __attribute__((ext_vector_type(2)));
typedef float f32x4 __attribute__((ext_vector_type(4)));

union H8 { f16x8 v; f16x2 p[4]; _Float16 h[8]; int4 i4; unsigned int w[4]; };

#if defined(__has_builtin)
#if __has_builtin(__builtin_amdgcn_fdot2)
#define HAS_FDOT2 1
#endif
#endif

__device__ __forceinline__ float dot2f(f16x2 a, f16x2 b, float c) {
#ifdef HAS_FDOT2
    return __builtin_amdgcn_fdot2(a, b, c, false);
#else
    return fmaf((float)a[0], (float)b[0], fmaf((float)a[1], (float)b[1], c));
#endif
}

__device__ __forceinline__ void fmix2(float& alo, float& ahi,
                                      unsigned int pk, float s) {
    asm("v_fma_mix_f32 %0, %1, %2, %0 op_sel:[0,0,0] op_sel_hi:[1,0,0]"
        : "+v"(alo) : "v"(pk), "v"(s));
    asm("v_fma_mix_f32 %0, %1, %2, %0 op_sel:[1,0,0] op_sel_hi:[1,0,0]"
        : "+v"(ahi) : "v"(pk), "v"(s));
}

// 16-lane allreduce via DPP row_ror (compile-time ctrl).
template <int CTRL>
__device__ __forceinline__ float rot_add(float x) {
    int t = __builtin_amdgcn_update_dpp(0, __builtin_bit_cast(int, x),
                                        CTRL, 0xf, 0xf, false);
    return x + __builtin_bit_cast(float, t);
}
__device__ __forceinline__ float reduce16(float q) {
    q = rot_add<0x121>(q);
    q = rot_add<0x122>(q);
    q = rot_add<0x124>(q);
    q = rot_add<0x128>(q);
    return q;
}

// ---------------------------------------------------------------------------
// Kernel 0 (fused setup): [0,160) convert_w, [160,2160) convert_x,
// [2160,6160) build_sparse.
// ---------------------------------------------------------------------------
__global__ __launch_bounds__(256) void setup_all(
    const float* __restrict__ W_list, const float* __restrict__ dense_W,
    const float* __restrict__ final_W,
    _Float16* __restrict__ wt_hi, _Float16* __restrict__ wt_lo,
    const float* __restrict__ x_in,
    _Float16* __restrict__ xh, _Float16* __restrict__ xl,
    const float* __restrict__ contacts,
    int* __restrict__ idx, int* __restrict__ cnt, float* __restrict__ adiag)
{
    __shared__ float T[64][68];
    int bid = blockIdx.x;
    int t = threadIdx.x;

    if (bid < 160) {
        int mat = bid >> 4;
        int tile = bid & 15;
        int tk = (tile >> 2) * 64, tn = (tile & 3) * 64;
        const float* src = (mat < 3) ? (W_list + (size_t)mat * 65536)
                         : (mat < 9) ? (dense_W + (size_t)(mat - 3) * 65536)
                                     : final_W;
        {
            int k = t >> 2, nc = (t & 3) * 16;
            const float* sp = src + (size_t)(tk + k) * 256 + tn + nc;
            *(float4*)&T[k][nc + 0]  = *(const float4*)(sp + 0);
            *(float4*)&T[k][nc + 4]  = *(const float4*)(sp + 4);
            *(float4*)&T[k][nc + 8]  = *(const float4*)(sp + 8);
            *(float4*)&T[k][nc + 12] = *(const float4*)(sp + 12);
        }
        __syncthreads();
        int n = t >> 2, kc = (t & 3) * 16;
        H8 hh0, hh1, ll0, ll1;
        #pragma unroll
        for (int i = 0; i < 16; ++i) {
            float x = T[kc + i][n];
            _Float16 hi = (_Float16)x;
            _Float16 lo = (_Float16)((x - (float)hi) * SPLIT_SCALE);
            if (i < 8) { hh0.h[i] = hi; ll0.h[i] = lo; }
            else       { hh1.h[i - 8] = hi; ll1.h[i - 8] = lo; }
        }
        size_t o = (size_t)mat * 65536 + (size_t)(tn + n) * 256 + tk + kc;
        *(int4*)(wt_hi + o)     = hh0.i4;
        *(int4*)(wt_hi + o + 8) = hh1.i4;
        *(int4*)(wt_lo + o)     = ll0.i4;
        *(int4*)(wt_lo + o + 8) = ll1.i4;
    } else if (bid < 2160) {
        size_t gid = (size_t)(bid - 160) * 256 + t;
        const float* p = x_in + gid * 8;
        float4 a = *(const float4*)p;
        float4 b = *(const float4*)(p + 4);
        float xs[8] = {a.x, a.y, a.z, a.w, b.x, b.y, b.z, b.w};
        H8 hh, ll;
        #pragma unroll
        for (int i = 0; i < 8; ++i) {
            _Float16 h = (_Float16)xs[i];
            hh.h[i] = h;
            ll.h[i] = (_Float16)((xs[i] - (float)h) * SPLIT_SCALE);
        }
        *(int4*)(xh + gid * 8) = hh.i4;
        *(int4*)(xl + gid * 8) = ll.i4;
    } else {
        int wave = (int)(((size_t)(bid - 2160) * 256 + t) >> 6);
        int lane = t & 63;
        int b = wave / NN;
        int i = wave - b * NN;
        const float* row = contacts + (size_t)b * NN * NN + (size_t)i * NN;
        int* out = idx + (size_t)wave * MAXNZ;
        int count = 0;
        for (int j0 = 0; j0 < NN; j0 += 64) {
            int j = j0 + lane;
            float v = (j < NN) ? row[j] : 0.0f;
            bool p = (v != 0.0f) && (j != i);
            unsigned long long bal = __ballot(p);
            if (p) {
                int pre = __popcll(bal & ((1ull << lane) - 1ull));
                out[count + pre] = j;
            }
            count += __popcll(bal);
        }
        if (lane == 0) {
            cnt[wave] = count;
            adiag[wave] = row[i] + 1.0f;
        }
    }
}

// ---------------------------------------------------------------------------
// Kernel 2: sparse attention aggregate v9 (frozen — gather/issue-bound).
// ---------------------------------------------------------------------------
__global__ __launch_bounds__(256, 3) void sparse_agg(
    const _Float16* __restrict__ yhi,
    const _Float16* __restrict__ xhi, const _Float16* __restrict__ xlo,
    const int* __restrict__ idx, const int* __restrict__ cnt,
    const float* __restrict__ adiag,
    _Float16* __restrict__ ohi, _Float16* __restrict__ olo)
{
    int bid = blockIdx.x;
    int xcd = bid & 7;
    int chunk = bid >> 3;
    int row = xcd * 2000 + chunk * 4 + (int)(threadIdx.x >> 6);
    row = __builtin_amdgcn_readfirstlane(row);
    int lane = threadIdx.x & 63;
    int g = lane >> 4, s = lane & 15;
    int b = row / NN;

    const _Float16* yp = yhi + (size_t)row * DD + s * 8;
    H8 yh0, yh1;
    yh0.i4 = *(const int4*)yp;
    yh1.i4 = *(const int4*)(yp + 128);

    const _Float16* xph = xhi + (size_t)row * DD + s * 8;
    const _Float16* xpl = xlo + (size_t)row * DD + s * 8;
    H8 xih0, xih1, xil0, xil1;
    xih0.i4 = *(const int4*)xph;       xih1.i4 = *(const int4*)(xph + 128);
    xil0.i4 = *(const int4*)xpl;       xil1.i4 = *(const int4*)(xpl + 128);
    float xi[16];
    #pragma unroll
    for (int u = 0; u < 8; ++u) {
        xi[u]     = fmaf((float)xil0.h[u], INV_SPLIT, (float)xih0.h[u]);
        xi[8 + u] = fmaf((float)xil1.h[u], INV_SPLIT, (float)xih1.h[u]);
    }
    const _Float16* xb = xhi + (size_t)b * NN * DD;

    float p = 0.0f;
    #pragma unroll
    for (int u = 0; u < 8; ++u) {
        p = fmaf((float)yh0.h[u], xi[u], p);
        p = fmaf((float)yh1.h[u], xi[8 + u], p);
    }
    p = reduce16(p);
    float wd = (g == 0) ? (__expf(p) + 1e-5f) * adiag[row] : 0.0f;
    float denom = wd;
    float acc[16];
    #pragma unroll
    for (int u = 0; u < 16; ++u) acc[u] = wd * xi[u];

    const int c = cnt[row];
    const int* ip = idx + (size_t)row * MAXNZ;
    const int iters = (c + 7) >> 3;

    int jA1, jB1;
    H8 vA0, vA1, vB0, vB1;
    {
        int ja = (g < c) ? ip[g] : 0;
        int jb = (4 + g < c) ? ip[4 + g] : 0;
        jA1 = (8 + g < c) ? ip[8 + g] : 0;
        jB1 = (12 + g < c) ? ip[12 + g] : 0;
        const _Float16* pa = xb + (size_t)ja * DD + s * 8;
        vA0.i4 = *(const int4*)pa;
        vA1.i4 = *(const int4*)(pa + 128);
        const _Float16* pb = xb + (size_t)jb * DD + s * 8;
        vB0.i4 = *(const int4*)pb;
        vB1.i4 = *(const int4*)(pb + 128);
    }

    for (int t = 0; t < iters; ++t) {
        int k2a = (t + 2) * 8 + g;
        int k2b = k2a + 4;
        int jA2 = (k2a < c) ? ip[k2a] : 0;
        int jB2 = (k2b < c) ? ip[k2b] : 0;
        H8 mA0, mA1, mB0, mB1;
        const _Float16* pa = xb + (size_t)jA1 * DD + s * 8;
        mA0.i4 = *(const int4*)pa;
        mA1.i4 = *(const int4*)(pa + 128);
        const _Float16* pb = xb + (size_t)jB1 * DD + s * 8;
        mB0.i4 = *(const int4*)pb;
        mB1.i4 = *(const int4*)(pb + 128);

        bool vokA = t * 8 + g < c;
        bool vokB = t * 8 + 4 + g < c;

        float qa0 = 0.0f, qa1 = 0.0f, qb0 = 0.0f, qb1 = 0.0f;
        #pragma unroll
        for (int i = 0; i < 4; ++i) {
            qa0 = dot2f(yh0.p[i], vA0.p[i], qa0);
            qa1 = dot2f(yh1.p[i], vA1.p[i], qa1);
            qb0 = dot2f(yh0.p[i], vB0.p[i], qb0);
            qb1 = dot2f(yh1.p[i], vB1.p[i], qb1);
        }
        float qa = reduce16(qa0 + qa1);
        float qb = reduce16(qb0 + qb1);
        float wa = vokA ? __expf(qa) : 0.0f;
        float wb = vokB ? __expf(qb) : 0.0f;
        denom += wa + wb;
        #pragma unroll
        for (int i = 0; i < 4; ++i) {
            fmix2(acc[2 * i],     acc[2 * i + 1],     vA0.w[i], wa);
            fmix2(acc[8 + 2 * i], acc[8 + 2 * i + 1], vA1.w[i], wa);
        }
        #pragma unroll
        for (int i = 0; i < 4; ++i) {
            fmix2(acc[2 * i],     acc[2 * i + 1],     vB0.w[i], wb);
            fmix2(acc[8 + 2 * i], acc[8 + 2 * i + 1], vB1.w[i], wb);
        }

        vA0 = mA0; vA1 = mA1; vB0 = mB0; vB1 = mB1;
        jA1 = jA2; jB1 = jB2;
    }

#define XG(x) x += __shfl_xor(x, 16); x += __shfl_xor(x, 32);
    XG(denom);
    #pragma unroll
    for (int u = 0; u < 16; ++u) { XG(acc[u]) }
#undef XG

    float inv = 1.0f / denom;
    int half = (g & 1) * 8;
    H8 st;
    #pragma unroll
    for (int i = 0; i < 8; ++i) {
        float x = acc[half + i] * inv;
        _Float16 h = (_Float16)x;
        st.h[i] = (g & 2) ? (_Float16)((x - (float)h) * SPLIT_SCALE) : h;
    }
    _Float16* dst = ((g & 2) ? olo : ohi) + (size_t)row * DD + (g & 1) * 128 + s * 8;
    *(int4*)dst = st.i4;
}

// ---------------------------------------------------------------------------
// Kernel 3: split-fp16 MFMA GEMM v9 = v8 + hi_only fast path.
// hi_only=1 (y-projections): A-hi x B-hi only — 1/3 MFMA, half staging.
// Scores are consumed at fp16 precision anyway (sparse_agg gathers xhi).
// ---------------------------------------------------------------------------
__global__ __launch_bounds__(512, 4) void gemm16(
    const _Float16* __restrict__ Ahi, const _Float16* __restrict__ Alo,
    const _Float16* __restrict__ Bhi, const _Float16* __restrict__ Blo,
    const float* __restrict__ bias,
    const _Float16* __restrict__ Shi, const _Float16* __restrict__ Slo,
    _Float16* __restrict__ Chi, _Float16* __restrict__ Clo,
    float* __restrict__ Cf32, int relu, int lo_write, int hi_only)
{
    __shared__ __align__(16) char smem[49152];
    char* Ah = smem;
    char* Al = smem + 16384;
    char* Bh = smem + 32768;
    char* Bl = smem + 40960;

    int tid = threadIdx.x;
    int mBase = blockIdx.y * 128;
    int nBase = blockIdx.x * 64;

    int ra = tid >> 2, ka = (tid & 3) * 16;
    const _Float16* gAh = Ahi + (size_t)(mBase + ra) * 256 + ka;
    const _Float16* gAl = Alo ? (Alo + (size_t)(mBase + ra) * 256 + ka) : gAh;
    int sbA = ra * 128 + ka * 2, swzA = (ra & 7) << 4;
    int rb = tid >> 3, kbb = (tid & 7) * 8;
    const _Float16* gBh = Bhi + (size_t)(nBase + rb) * 256 + kbb;
    const _Float16* gBl = Blo ? (Blo + (size_t)(nBase + rb) * 256 + kbb) : gBh;
    int sbB = rb * 128 + kbb * 2, swzB = (rb & 7) << 4;

    int l = tid & 63, wv = tid >> 6;
    int wm = (wv & 3) * 32, wn = (wv >> 2) * 32;
    int lr = l & 15, lk = l >> 4;

    f32x4 acc0[2][2] = {};
    f32x4 acc1[2][2] = {};

    int4 rA0, rA1, rA2, rA3, rB0, rB1;
#define LOADG(kb) \
    rA0 = *(const int4*)(gAh + (kb));     rA1 = *(const int4*)(gAh + (kb) + 8); \
    rB0 = *(const int4*)(gBh + (kb)); \
    if (!hi_only) { \
        rA2 = *(const int4*)(gAl + (kb)); rA3 = *(const int4*)(gAl + (kb) + 8); \
        rB1 = *(const int4*)(gBl + (kb)); \
    }

    LOADG(0)

    #pragma unroll
    for (int kb = 0; kb < 256; kb += 64) {
        __syncthreads();
        *(int4*)(Ah + ((sbA +  0) ^ swzA)) = rA0;
        *(int4*)(Ah + ((sbA + 16) ^ swzA)) = rA1;
        *(int4*)(Bh + (sbB ^ swzB)) = rB0;
        if (!hi_only) {
            *(int4*)(Al + ((sbA +  0) ^ swzA)) = rA2;
            *(int4*)(Al + ((sbA + 16) ^ swzA)) = rA3;
            *(int4*)(Bl + (sbB ^ swzB)) = rB1;
        }
        __syncthreads();

        if (kb < 192) { LOADG(kb + 64) }

        #pragma unroll
        for (int kk = 0; kk < 2; ++kk) {
            int kby = kk * 64 + lk * 16;
            f16x8 fah[2], fal[2], fbh[2], fbl[2];
            #pragma unroll
            for (int mt = 0; mt < 2; ++mt) {
                int ml = wm + mt * 16 + lr;
                int off = (ml * 128 + kby) ^ ((ml & 7) << 4);
                fah[mt] = *(const f16x8*)(Ah + off);
                if (!hi_only) fal[mt] = *(const f16x8*)(Al + off);
            }
            #pragma unroll
            for (int nt = 0; nt < 2; ++nt) {
                int nl = wn + nt * 16 + lr;
                int off = (nl * 128 + kby) ^ ((nl & 7) << 4);
                fbh[nt] = *(const f16x8*)(Bh + off);
                if (!hi_only) fbl[nt] = *(const f16x8*)(Bl + off);
            }
            #pragma unroll
            for (int mt = 0; mt < 2; ++mt)
                #pragma unroll
                for (int nt = 0; nt < 2; ++nt) {
                    acc0[mt][nt] = __builtin_amdgcn_mfma_f32_16x16x32_f16(
                        fah[mt], fbh[nt], acc0[mt][nt], 0, 0, 0);
                    if (!hi_only) {
                        acc1[mt][nt] = __builtin_amdgcn_mfma_f32_16x16x32_f16(
                            fah[mt], fbl[nt], acc1[mt][nt], 0, 0, 0);
                        acc1[mt][nt] = __builtin_amdgcn_mfma_f32_16x16x32_f16(
                            fal[mt], fbh[nt], acc1[mt][nt], 0, 0, 0);
                    }
                }
        }
    }
#undef LOADG

    __syncthreads();
    float* T = (float*)smem;
    #pragma unroll
    for (int mt = 0; mt < 2; ++mt)
        #pragma unroll
        for (int nt = 0; nt < 2; ++nt)
            #pragma unroll
            for (int q = 0; q < 4; ++q) {
                int m = wm + mt * 16 + lk * 4 + q;
                int n = wn + nt * 16 + lr;
                float v = acc0[mt][nt][q];
                if (!hi_only) v += acc1[mt][nt][q] * INV_SPLIT;
                T[m * 68 + n] = v;
            }
    __syncthreads();

    {
        int rr = tid >> 2;
        int c0 = (tid & 3) * 16;
        int m = mBase + rr;
        size_t o = (size_t)m * 256 + nBase + c0;
        float v[16];
        #pragma unroll
        for (int i = 0; i < 4; ++i) {
            float4 f = *(const float4*)&T[rr * 68 + c0 + i * 4];
            v[i * 4 + 0] = f.x; v[i * 4 + 1] = f.y;
            v[i * 4 + 2] = f.z; v[i * 4 + 3] = f.w;
        }
        if (bias) {
            #pragma unroll
            for (int i = 0; i < 4; ++i) {
                float4 bv = *(const float4*)(bias + nBase + c0 + i * 4);
                v[i * 4 + 0] += bv.x; v[i * 4 + 1] += bv.y;
                v[i * 4 + 2] += bv.z; v[i * 4 + 3] += bv.w;
            }
        }
        if (relu) {
            #pragma unroll
            for (int i = 0; i < 16; ++i) v[i] = fmaxf(v[i], 0.0f);
        }
        if (Shi) {
            #pragma unroll
            for (int j = 0; j < 2; ++j) {
                H8 sh, sl;
                sh.i4 = *(const int4*)(Shi + o + j * 8);
                sl.i4 = *(const int4*)(Slo + o + j * 8);
                #pragma unroll
                for (int u = 0; u < 8; ++u)
                    v[j * 8 + u] += fmaf((float)sl.h[u], INV_SPLIT, (float)sh.h[u]);
            }
        }
        if (Cf32) {
            #pragma unroll
            for (int i = 0; i < 4; ++i) {
                *(float4*)(Cf32 + o + i * 4) =
                    make_float4(v[i * 4], v[i * 4 + 1], v[i * 4 + 2], v[i * 4 + 3]);
            }
        } else {
            #pragma unroll
            for (int j = 0; j < 2; ++j) {
                H8 hh;
                #pragma unroll
                for (int u = 0; u < 8; ++u) hh.h[u] = (_Float16)v[j * 8 + u];
                *(int4*)(Chi + o + j * 8) = hh.i4;
            }
            if (lo_write) {
                #pragma unroll
                for (int j = 0; j < 2; ++j) {
                    H8 ll;
                    #pragma unroll
                    for (int u = 0; u < 8; ++u) {
                        float x = v[j * 8 + u];
                        ll.h[u] = (_Float16)((x - (float)(_Float16)x) * SPLIT_SCALE);
                    }
                    *(int4*)(Clo + o + j * 8) = ll.i4;
                }
            }
        }
    }
}

// ---------------------------------------------------------------------------
extern "C" void kernel_launch(void* const* d_in, const int* in_sizes, int n_in,
                              void* d_out, int out_size, void* d_ws, size_t ws_size,
                              hipStream_t stream)
{
    const float* x_in     = (const float*)d_in[0];
    const float* contacts = (const float*)d_in[1];
    const float* W_list   = (const float*)d_in[2];
    const float* dense_W  = (const float*)d_in[3];
    const float* dense_b  = (const float*)d_in[4];
    const float* final_W  = (const float*)d_in[5];
    const float* final_b  = (const float*)d_in[6];
    float* out = (float*)d_out;

    char* ws = (char*)d_ws;
    const size_t PL = (size_t)MROWS * DD;
    _Float16* pl[8];
    for (int i = 0; i < 8; ++i) pl[i] = (_Float16*)ws + (size_t)i * PL;
    char* p8 = ws + 8 * PL * sizeof(_Float16);
    int*   idx   = (int*)p8;
    int*   cnt   = (int*)(p8 + (size_t)MROWS * MAXNZ * sizeof(int));
    float* adiag = (float*)((char*)cnt + (size_t)MROWS * sizeof(int));
    _Float16* wt_hi = (_Float16*)((char*)adiag + (size_t)MROWS * sizeof(float));
    _Float16* wt_lo = wt_hi + (size_t)10 * 65536;

    setup_all<<<6160, 256, 0, stream>>>(W_list, dense_W, final_W, wt_hi, wt_lo,
                                        x_in, pl[0], pl[1],
                                        contacts, idx, cnt, adiag);

    dim3 gg(4, MROWS / 128);   // (4, 125) = 500 blocks x 512 threads
    int cur = 0;
    for (int l = 0; l < LL; ++l) {
        int oth = 1 - cur;
        _Float16 *x0h = pl[2 * cur], *x0l = pl[2 * cur + 1];
        _Float16 *yh  = pl[2 * oth], *yl  = pl[2 * oth + 1];
        _Float16 *xah = pl[4], *xal = pl[5];
        _Float16 *xbh = pl[6], *xbl = pl[7];
        // y = x0 @ W_l  — hi-only inputs AND output (scores are fp16-path)
        gemm16<<<gg, 512, 0, stream>>>(x0h, nullptr,
                                       wt_hi + (size_t)l * 65536, nullptr,
                                       nullptr, nullptr, nullptr,
                                       yh, yl, nullptr, 0, 0, 1);
        // sparse attention aggregate
        sparse_agg<<<MROWS / 4, 256, 0, stream>>>(yh, x0h, x0l, idx, cnt, adiag,
                                                  xah, xal);
        // dense 1 (relu) — full split precision
        gemm16<<<gg, 512, 0, stream>>>(xah, xal,
                                       wt_hi + (size_t)(3 + l * 2) * 65536,
                                       wt_lo + (size_t)(3 + l * 2) * 65536,
                                       dense_b + (size_t)(l * 2 + 0) * 256,
                                       nullptr, nullptr,
                                       xbh, xbl, nullptr, 1, 1, 0);
        // dense 2 (relu) + skip(x0) -> next X0
        gemm16<<<gg, 512, 0, stream>>>(xbh, xbl,
                                       wt_hi + (size_t)(4 + l * 2) * 65536,
                                       wt_lo + (size_t)(4 + l * 2) * 65536,
                                       dense_b + (size_t)(l * 2 + 1) * 256,
                                       x0h, x0l,
                                       yh, yl, nullptr, 1, 1, 0);
        cur = oth;
    }
    // final projection -> fp32 d_out (full split precision)
    gemm16<<<gg, 512, 0, stream>>>(pl[2 * cur], pl[2 * cur + 1],
                                   wt_hi + (size_t)9 * 65536,
                                   wt_lo + (size_t)9 * 65536,
                                   final_b, nullptr, nullptr,
                                   nullptr, nullptr, out, 0, 0, 0);
}